// Round 1
// baseline (32.070 us; speedup 1.0000x reference)
//
#include <hip/hip_runtime.h>

typedef __attribute__((ext_vector_type(8))) short bf16x8;
typedef __attribute__((ext_vector_type(4))) float f32x4;

__device__ __forceinline__ short f2bf(float x) {
    union { float f; unsigned u; } v; v.f = x;
    unsigned r = v.u + 0x7FFFu + ((v.u >> 16) & 1u);   // round-to-nearest-even bf16
    return (short)(r >> 16);
}

// C_partial[chunk][m][n] = sum_{k in chunk} A[m][k] * W[n][k]
// M = 4096, N = 32, K = 1024.
// TRANS=false: A[m][k] = Abase[m*1024 + k]                      (seq: m=b*S+s, k=h)
// TRANS=true : A[m][k] = Abase[((m>>10)<<20) + k*1024 + (m&1023)] (hid: m=b*H+h, k=s)
// Per wave: one 16-row M-tile, both 16-col N-tiles, K-chunk of ksteps*32.
// MFMA k-slot mapping kg(g,j)=8g+j used identically for A and B fragments ->
// result invariant to the HW's internal k permutation.
template<bool TRANS>
__global__ __launch_bounds__(256) void gemm_skinny(
    const float* __restrict__ A, const float* __restrict__ W,
    float* __restrict__ P, int ksteps)
{
    const int tid  = threadIdx.x;
    const int wv   = tid >> 6;
    const int l    = tid & 63;
    const int l15  = l & 15;
    const int g    = l >> 4;
    const int m0   = (blockIdx.x * 4 + wv) * 16;
    const int mrow = m0 + l15;
    const int chunk = blockIdx.y;
    const int kc0  = chunk * (ksteps * 32);

    size_t arow;
    if (TRANS) arow = ((size_t)(mrow >> 10) << 20) + (size_t)(mrow & 1023);
    else       arow = (size_t)mrow << 10;

    f32x4 acc0 = {0.f,0.f,0.f,0.f}, acc1 = {0.f,0.f,0.f,0.f};

    for (int ks = 0; ks < ksteps; ++ks) {
        const int kb = kc0 + ks * 32 + g * 8;
        bf16x8 af, bf0, bf1;
        if (TRANS) {
            const float* pa = A + arow + (size_t)kb * 1024;
            #pragma unroll
            for (int j = 0; j < 8; ++j) af[j] = f2bf(pa[(size_t)j * 1024]);
        } else {
            const f32x4* pa = (const f32x4*)(A + arow + kb);
            f32x4 a0 = pa[0], a1 = pa[1];
            af[0]=f2bf(a0.x); af[1]=f2bf(a0.y); af[2]=f2bf(a0.z); af[3]=f2bf(a0.w);
            af[4]=f2bf(a1.x); af[5]=f2bf(a1.y); af[6]=f2bf(a1.z); af[7]=f2bf(a1.w);
        }
        {
            const f32x4* pb = (const f32x4*)(W + (size_t)l15 * 1024 + kb);
            f32x4 b0 = pb[0], b1 = pb[1];
            bf0[0]=f2bf(b0.x); bf0[1]=f2bf(b0.y); bf0[2]=f2bf(b0.z); bf0[3]=f2bf(b0.w);
            bf0[4]=f2bf(b1.x); bf0[5]=f2bf(b1.y); bf0[6]=f2bf(b1.z); bf0[7]=f2bf(b1.w);
        }
        {
            const f32x4* pb = (const f32x4*)(W + (size_t)(l15 + 16) * 1024 + kb);
            f32x4 b0 = pb[0], b1 = pb[1];
            bf1[0]=f2bf(b0.x); bf1[1]=f2bf(b0.y); bf1[2]=f2bf(b0.z); bf1[3]=f2bf(b0.w);
            bf1[4]=f2bf(b1.x); bf1[5]=f2bf(b1.y); bf1[6]=f2bf(b1.z); bf1[7]=f2bf(b1.w);
        }
        acc0 = __builtin_amdgcn_mfma_f32_16x16x32_bf16(af, bf0, acc0, 0, 0, 0);
        acc1 = __builtin_amdgcn_mfma_f32_16x16x32_bf16(af, bf1, acc1, 0, 0, 0);
    }

    // C/D layout (m89-verified): col = lane&15, row = (lane>>4)*4 + reg
    float* Pc = P + (size_t)chunk * 4096 * 32;
    #pragma unroll
    for (int r = 0; r < 4; ++r) {
        const int m = m0 + 4 * g + r;
        Pc[(size_t)m * 32 + l15]      = acc0[r];
        Pc[(size_t)m * 32 + 16 + l15] = acc1[r];
    }
}

// Reduce partial chunks: Rd[half][m][n] = sum_c P[half][c][m][n]
__global__ __launch_bounds__(256) void kreduce(const float* __restrict__ P,
                                               float* __restrict__ Rd, int nch)
{
    const int fi   = blockIdx.x * 256 + threadIdx.x;  // 0..65535 (f4 units)
    const int half = fi >> 15;
    const int wi   = fi & 32767;
    const f32x4* src = (const f32x4*)P + (size_t)half * nch * 32768 + wi;
    f32x4 acc = {0.f,0.f,0.f,0.f};
    for (int c = 0; c < nch; ++c) acc += src[(size_t)c * 32768];
    ((f32x4*)Rd)[fi] = acc;
}

// out[b][s][h] = sum_r seqE[b*1024+s][r]*w[r] * hidE[b*1024+h][r]
// Block: b x (32-s tile) x (64-h tile). 256 threads.
__global__ __launch_bounds__(256) void k3(const float* __restrict__ SeqE,
                                          const float* __restrict__ HidE,
                                          const float* __restrict__ cpw,
                                          float* __restrict__ out)
{
    __shared__ float s_w[32][36];   // seq tile, pre-weighted
    __shared__ float s_h[64][36];   // hid tile
    const int tid = threadIdx.x;
    const int b  = blockIdx.z;
    const int s0 = blockIdx.x * 32;
    const int h0 = blockIdx.y * 64;

    {   // stage seq tile: 32 rows x 32 r = 256 f4, one per thread
        const int si = tid >> 3;
        const int r4 = (tid & 7) * 4;
        f32x4 v  = *(const f32x4*)(SeqE + ((size_t)(b * 1024 + s0 + si)) * 32 + r4);
        f32x4 wv = *(const f32x4*)(cpw + r4);
        v *= wv;
        *(f32x4*)&s_w[si][r4] = v;
    }
    #pragma unroll
    for (int t = 0; t < 2; ++t) {   // stage hid tile: 64 x 32 = 512 f4
        const int fi = tid + t * 256;
        const int hx = fi >> 3;
        const int r4 = (fi & 7) * 4;
        f32x4 v = *(const f32x4*)(HidE + ((size_t)(b * 1024 + h0 + hx)) * 32 + r4);
        *(f32x4*)&s_h[hx][r4] = v;
    }
    __syncthreads();

    const int hx = tid & 63;
    const int sg = tid >> 6;
    float hv[32];
    #pragma unroll
    for (int r4 = 0; r4 < 32; r4 += 4) {
        f32x4 v = *(const f32x4*)&s_h[hx][r4];
        hv[r4] = v.x; hv[r4+1] = v.y; hv[r4+2] = v.z; hv[r4+3] = v.w;
    }
    float res[8];
    #pragma unroll
    for (int si = 0; si < 8; ++si) {
        const int s = sg * 8 + si;
        float acc = 0.f;
        #pragma unroll
        for (int r4 = 0; r4 < 32; r4 += 4) {
            f32x4 v = *(const f32x4*)&s_w[s][r4];   // broadcast across lanes
            acc += v.x * hv[r4] + v.y * hv[r4+1] + v.z * hv[r4+2] + v.w * hv[r4+3];
        }
        res[si] = acc;
    }
    #pragma unroll
    for (int si = 0; si < 8; ++si) {
        const int s = s0 + sg * 8 + si;
        out[((size_t)(b * 1024 + s)) * 1024 + h0 + hx] = res[si];
    }
}

extern "C" void kernel_launch(void* const* d_in, const int* in_sizes, int n_in,
                              void* d_out, int out_size, void* d_ws, size_t ws_size,
                              hipStream_t stream) {
    const float* hs   = (const float*)d_in[0];
    // d_in[1] = all_indices: identically (n/H, n%H) -> computed implicitly
    const float* seqW = (const float*)d_in[2];
    const float* hidW = (const float*)d_in[3];
    const float* cpw  = (const float*)d_in[4];
    float* out = (float*)d_out;

    const size_t per = (size_t)4096 * 32 * 4;    // 512 KB per chunk-slice
    int nch = 8;
    while (nch > 1 && (2u * nch * per + 2 * per) > ws_size) nch >>= 1;
    const int kpc = (1024 / nch) / 32;           // k-steps per chunk

    float* Pseq = (float*)d_ws;                       // [nch][4096][32]
    float* Phid = Pseq + (size_t)nch * 4096 * 32;     // [nch][4096][32]
    float* Rd   = Phid + (size_t)nch * 4096 * 32;     // [2][4096][32]

    dim3 grid1(64, nch);
    gemm_skinny<false><<<grid1, 256, 0, stream>>>(hs, seqW, Pseq, kpc);
    gemm_skinny<true ><<<grid1, 256, 0, stream>>>(hs, hidW, Phid, kpc);
    kreduce<<<256, 256, 0, stream>>>(Pseq, Rd, nch);
    dim3 grid3(32, 16, 4);
    k3<<<grid3, 256, 0, stream>>>(Rd, Rd + 4096 * 32, cpw, out);
}

// Round 2
// 25.562 us; speedup vs baseline: 1.2546x; 1.2546x over previous
//
#include <hip/hip_runtime.h>

typedef __attribute__((ext_vector_type(8))) short bf16x8;
typedef __attribute__((ext_vector_type(4))) float f32x4;
typedef __attribute__((ext_vector_type(2))) float f32x2;

__device__ __forceinline__ short f2bf(float x) {
    union { float f; unsigned u; } v; v.f = x;
    unsigned r = v.u + 0x7FFFu + ((v.u >> 16) & 1u);   // round-to-nearest-even bf16
    return (short)(r >> 16);
}

// Fused skinny GEMMs, full-K per block.
//   blocks 0..255  : seqE[m][r] = sum_k hs[m*1024+k]          * seqW[r][k]   (m=b*S+s, k=h)
//   blocks 256..511: hidE[m][r] = sum_k hs[b*2^20 + k*1024+h] * hidW[r][k]   (m=b*H+h, k=s)
// 4 waves/block, wave w owns K-slice [w*256, w*256+256) of the SAME 16-row tile;
// LDS reduce across waves writes final fp32 embeddings (no partial round-trip).
// MFMA k-slot mapping kg(g,j)=8g+j used identically for A and B fragments ->
// result invariant to the HW's internal k permutation.
__global__ __launch_bounds__(256) void gemm_fused(
    const float* __restrict__ hs, const float* __restrict__ seqW,
    const float* __restrict__ hidW, float* __restrict__ E /* [2][4096][32] */)
{
    __shared__ float red[4][16][32];

    const int bid = blockIdx.x;
    const bool hid = bid >= 256;
    const int mt  = hid ? bid - 256 : bid;
    const int tid = threadIdx.x;
    const int wv  = tid >> 6;
    const int l   = tid & 63;
    const int l15 = l & 15;
    const int g   = l >> 4;
    const int m0  = mt * 16;
    const int mrow = m0 + l15;

    const float* __restrict__ W = hid ? hidW : seqW;
    size_t arow;
    if (hid) arow = ((size_t)(mrow >> 10) << 20) + (size_t)(mrow & 1023);
    else     arow = (size_t)mrow << 10;

    f32x4 acc0 = {0.f,0.f,0.f,0.f}, acc1 = {0.f,0.f,0.f,0.f};
    const int kbase = wv * 256;

    for (int ks = 0; ks < 8; ++ks) {
        const int kb = kbase + ks * 32 + g * 8;
        bf16x8 af, bf0, bf1;
        if (hid) {
            const float* pa = hs + arow + (size_t)kb * 1024;
            #pragma unroll
            for (int j = 0; j < 8; ++j) af[j] = f2bf(pa[(size_t)j * 1024]);
        } else {
            const f32x4* pa = (const f32x4*)(hs + arow + kb);
            f32x4 a0 = pa[0], a1 = pa[1];
            af[0]=f2bf(a0.x); af[1]=f2bf(a0.y); af[2]=f2bf(a0.z); af[3]=f2bf(a0.w);
            af[4]=f2bf(a1.x); af[5]=f2bf(a1.y); af[6]=f2bf(a1.z); af[7]=f2bf(a1.w);
        }
        {
            const f32x4* pb = (const f32x4*)(W + (size_t)l15 * 1024 + kb);
            f32x4 b0 = pb[0], b1 = pb[1];
            bf0[0]=f2bf(b0.x); bf0[1]=f2bf(b0.y); bf0[2]=f2bf(b0.z); bf0[3]=f2bf(b0.w);
            bf0[4]=f2bf(b1.x); bf0[5]=f2bf(b1.y); bf0[6]=f2bf(b1.z); bf0[7]=f2bf(b1.w);
        }
        {
            const f32x4* pb = (const f32x4*)(W + (size_t)(l15 + 16) * 1024 + kb);
            f32x4 b0 = pb[0], b1 = pb[1];
            bf1[0]=f2bf(b0.x); bf1[1]=f2bf(b0.y); bf1[2]=f2bf(b0.z); bf1[3]=f2bf(b0.w);
            bf1[4]=f2bf(b1.x); bf1[5]=f2bf(b1.y); bf1[6]=f2bf(b1.z); bf1[7]=f2bf(b1.w);
        }
        acc0 = __builtin_amdgcn_mfma_f32_16x16x32_bf16(af, bf0, acc0, 0, 0, 0);
        acc1 = __builtin_amdgcn_mfma_f32_16x16x32_bf16(af, bf1, acc1, 0, 0, 0);
    }

    // C/D layout (m89-verified): col = lane&15, row = (lane>>4)*4 + reg
    #pragma unroll
    for (int r = 0; r < 4; ++r) {
        red[wv][4 * g + r][l15]      = acc0[r];
        red[wv][4 * g + r][l15 + 16] = acc1[r];
    }
    __syncthreads();

    // Sum 4 wave-partials; each thread produces 2 consecutive outputs (f32x2 store).
    const int o = tid * 2;
    const float* rf = &red[0][0][0];
    f32x2 v;
    v.x = rf[o]     + rf[512 + o]     + rf[1024 + o]     + rf[1536 + o];
    v.y = rf[o + 1] + rf[512 + o + 1] + rf[1024 + o + 1] + rf[1536 + o + 1];
    float* Eo = E + (hid ? (size_t)4096 * 32 : 0) + (size_t)m0 * 32 + o;
    *(f32x2*)Eo = v;
}

// out[b][s][h] = sum_r seqE[b*1024+s][r]*w[r] * hidE[b*1024+h][r]
// Block: b x (32-s tile) x (64-h tile). 256 threads.
__global__ __launch_bounds__(256) void k3(const float* __restrict__ SeqE,
                                          const float* __restrict__ HidE,
                                          const float* __restrict__ cpw,
                                          float* __restrict__ out)
{
    __shared__ float s_w[32][36];   // seq tile, pre-weighted
    __shared__ float s_h[64][36];   // hid tile
    const int tid = threadIdx.x;
    const int b  = blockIdx.z;
    const int s0 = blockIdx.x * 32;
    const int h0 = blockIdx.y * 64;

    {   // stage seq tile: 32 rows x 32 r = 256 f4, one per thread
        const int si = tid >> 3;
        const int r4 = (tid & 7) * 4;
        f32x4 v  = *(const f32x4*)(SeqE + ((size_t)(b * 1024 + s0 + si)) * 32 + r4);
        f32x4 wv = *(const f32x4*)(cpw + r4);
        v *= wv;
        *(f32x4*)&s_w[si][r4] = v;
    }
    #pragma unroll
    for (int t = 0; t < 2; ++t) {   // stage hid tile: 64 x 32 = 512 f4
        const int fi = tid + t * 256;
        const int hx = fi >> 3;
        const int r4 = (fi & 7) * 4;
        f32x4 v = *(const f32x4*)(HidE + ((size_t)(b * 1024 + h0 + hx)) * 32 + r4);
        *(f32x4*)&s_h[hx][r4] = v;
    }
    __syncthreads();

    const int hx = tid & 63;
    const int sg = tid >> 6;
    float hv[32];
    #pragma unroll
    for (int r4 = 0; r4 < 32; r4 += 4) {
        f32x4 v = *(const f32x4*)&s_h[hx][r4];
        hv[r4] = v.x; hv[r4+1] = v.y; hv[r4+2] = v.z; hv[r4+3] = v.w;
    }
    float res[8];
    #pragma unroll
    for (int si = 0; si < 8; ++si) {
        const int s = sg * 8 + si;
        float acc = 0.f;
        #pragma unroll
        for (int r4 = 0; r4 < 32; r4 += 4) {
            f32x4 v = *(const f32x4*)&s_w[s][r4];   // broadcast across lanes
            acc += v.x * hv[r4] + v.y * hv[r4+1] + v.z * hv[r4+2] + v.w * hv[r4+3];
        }
        res[si] = acc;
    }
    #pragma unroll
    for (int si = 0; si < 8; ++si) {
        const int s = s0 + sg * 8 + si;
        out[((size_t)(b * 1024 + s)) * 1024 + h0 + hx] = res[si];
    }
}

extern "C" void kernel_launch(void* const* d_in, const int* in_sizes, int n_in,
                              void* d_out, int out_size, void* d_ws, size_t ws_size,
                              hipStream_t stream) {
    const float* hs   = (const float*)d_in[0];
    // d_in[1] = all_indices: identically (n/H, n%H) -> computed implicitly
    const float* seqW = (const float*)d_in[2];
    const float* hidW = (const float*)d_in[3];
    const float* cpw  = (const float*)d_in[4];
    float* out = (float*)d_out;

    float* E = (float*)d_ws;              // [2][4096][32] fp32, 1 MB

    gemm_fused<<<512, 256, 0, stream>>>(hs, seqW, hidW, E);
    dim3 grid3(32, 16, 4);
    k3<<<grid3, 256, 0, stream>>>(E, E + (size_t)4096 * 32, cpw, out);
}